// Round 5
// baseline (424.913 us; speedup 1.0000x reference)
//
#include <hip/hip_runtime.h>
#include <stdint.h>

typedef unsigned short u16;
typedef uint32_t u32;
typedef __attribute__((ext_vector_type(8))) short short8;
typedef __attribute__((ext_vector_type(4))) float f32x4;
typedef __attribute__((ext_vector_type(4))) u32 u32x4;
typedef __attribute__((ext_vector_type(4))) unsigned short u16x4;

#define BS_ 4096   // B*S rows
#define S_ 2048
#define HID_ 2048
#define KVB 64

__device__ __forceinline__ float bf2f(u16 u) { union { u32 i; float f; } v; v.i = ((u32)u) << 16; return v.f; }
__device__ __forceinline__ u16 f2bf(float f) {
  union { float f; u32 i; } v; v.f = f;
  u32 r = v.i + 0x7fffu + ((v.i >> 16) & 1u);
  return (u16)(r >> 16);
}

__device__ __forceinline__ void gload16(const void* gsrc, void* ldst) {
  __builtin_amdgcn_global_load_lds(
      (const __attribute__((address_space(1))) void*)gsrc,
      (__attribute__((address_space(3))) void*)ldst, 16, 0, 0);
}

// ---------------- elementwise convert fp32 -> bf16 ----------------
__global__ __launch_bounds__(256) void conv_f2b(const float* __restrict__ in, u16* __restrict__ out, int n4) {
  int i = blockIdx.x * 256 + threadIdx.x;
  if (i < n4) {
    float4 v = ((const float4*)in)[i];
    u16x4 o;
    o.x = f2bf(v.x); o.y = f2bf(v.y); o.z = f2bf(v.z); o.w = f2bf(v.w);
    ((u16x4*)out)[i] = o;
  }
}

// ---------------- transpose + convert: W[K][N] fp32 -> WT[N][K] bf16 ----------------
__global__ __launch_bounds__(256) void transpose_conv(const float* __restrict__ W, u16* __restrict__ WT,
                                                      int K, int N) {
  __shared__ float tile[64][65];
  const int t = threadIdx.x;
  const int kb = blockIdx.y * 64, nb = blockIdx.x * 64;
#pragma unroll
  for (int c = 0; c < 4; ++c) {
    int idx = c * 256 + t;
    int row = idx >> 4;
    int col4 = (idx & 15) * 4;
    float4 v = *(const float4*)&W[(size_t)(kb + row) * N + nb + col4];
    tile[row][col4 + 0] = v.x; tile[row][col4 + 1] = v.y;
    tile[row][col4 + 2] = v.z; tile[row][col4 + 3] = v.w;
  }
  __syncthreads();
#pragma unroll
  for (int c = 0; c < 4; ++c) {
    int idx = c * 256 + t;
    int n = idx >> 4;
    int k4 = (idx & 15) * 4;
    u16x4 o;
    o.x = f2bf(tile[k4 + 0][n]); o.y = f2bf(tile[k4 + 1][n]);
    o.z = f2bf(tile[k4 + 2][n]); o.w = f2bf(tile[k4 + 3][n]);
    *(u16x4*)&WT[(size_t)(nb + n) * K + kb + k4] = o;
  }
}

// ---------------- V transpose: vb[b][s][h*128+d] -> VT[(b*16+h)][d][s] ----------------
__global__ __launch_bounds__(256) void vtrans(const u16* __restrict__ Vin, u16* __restrict__ VT) {
  __shared__ u16 tile[64][136];
  const int t = threadIdx.x;
  const int st0 = blockIdx.x * 64;
  const int bh = blockIdx.y;
  const int bb = bh >> 4, h = bh & 15;
  const u16* src = Vin + (size_t)bb * S_ * HID_ + (size_t)h * 128;
  u16* dst = VT + (size_t)bh * 128 * S_;
#pragma unroll
  for (int c = 0; c < 4; ++c) {
    int idx = c * 256 + t;
    int s = idx >> 4, ch = idx & 15;
    short8 v = *(const short8*)&src[(size_t)(st0 + s) * HID_ + ch * 8];
    *(short8*)&tile[s][ch * 8] = v;
  }
  __syncthreads();
#pragma unroll
  for (int c = 0; c < 4; ++c) {
    int idx = c * 256 + t;
    int d = idx >> 3, ch = idx & 7;
    short8 o;
#pragma unroll
    for (int j = 0; j < 8; ++j) o[j] = tile[ch * 8 + j][d];
    *(short8*)&dst[(size_t)d * S_ + st0 + ch * 8] = o;
  }
}

// ---------------- RoPE table ----------------
__global__ __launch_bounds__(256) void rope_table(float* __restrict__ ct, float* __restrict__ st) {
  int idx = blockIdx.x * 256 + threadIdx.x;
  int pos = idx >> 6, i = idx & 63;
  float inv = powf(10000.f, -(float)i / 64.f);
  float a = (float)pos * inv;
  ct[idx] = cosf(a);
  st[idx] = sinf(a);
}

// ---------------- RoPE apply ----------------
__global__ __launch_bounds__(256) void rope_apply(u32* __restrict__ buf, const float* __restrict__ ct,
                                                  const float* __restrict__ st) {
  int idx = blockIdx.x * 256 + threadIdx.x;
  int s = (idx >> 10) & 2047;
  int i = idx & 63;
  u32 v = buf[idx];
  float x1 = bf2f((u16)(v & 0xffff)), x2 = bf2f((u16)(v >> 16));
  float c = ct[s * 64 + i], sn = st[s * 64 + i];
  float o1 = x1 * c - x2 * sn;
  float o2 = x1 * sn + x2 * c;
  buf[idx] = (u32)f2bf(o1) | ((u32)f2bf(o2) << 16);
}

// ---------------- GEMM (m97-structure + XCD-aware block swizzle) ----------------
template <int OUTF32>
__global__ __launch_bounds__(256) void gemm_bt(const u16* __restrict__ A, const u16* __restrict__ BT,
                                               const float* __restrict__ bias, void* __restrict__ Cout,
                                               int M, int N, int K) {
  __shared__ u16 As[128 * 64];
  __shared__ u16 Bs[128 * 64];
  const int t = threadIdx.x;
  const int lane = t & 63, wave = t >> 6;
  const int wm = wave >> 1, wn = wave & 1;
  // XCD swizzle: same-XCD blocks get consecutive logical tiles (nwg % 8 == 0 for all launches)
  const int gx = gridDim.x;
  const int nwg = gx * gridDim.y;
  const int flat = blockIdx.y * gx + blockIdx.x;
  const int swz = (flat & 7) * (nwg >> 3) + (flat >> 3);
  const int tn = swz % gx, tm = swz / gx;
  const int r16 = lane & 15, q4 = lane >> 4;

  f32x4 acc[4][4];
#pragma unroll
  for (int m = 0; m < 4; ++m)
#pragma unroll
    for (int n = 0; n < 4; ++n) acc[m][n] = (f32x4){0.f, 0.f, 0.f, 0.f};

  for (int kt = 0; kt < K; kt += 64) {
#pragma unroll
    for (int c = 0; c < 4; ++c) {
      int idx = c * 256 + t;
      int row = idx >> 3, ch = idx & 7;
      gload16(&A[(size_t)(tm * 128 + row) * K + kt + ch * 8], (char*)As + idx * 16);
      gload16(&BT[(size_t)(tn * 128 + row) * K + kt + ch * 8], (char*)Bs + idx * 16);
    }
    __syncthreads();
#pragma unroll
    for (int kk = 0; kk < 64; kk += 32) {
      short8 af[4], bfv[4];
#pragma unroll
      for (int m = 0; m < 4; ++m)
        af[m] = *(const short8*)&As[(wm * 64 + m * 16 + r16) * 64 + kk + q4 * 8];
#pragma unroll
      for (int n = 0; n < 4; ++n)
        bfv[n] = *(const short8*)&Bs[(wn * 64 + n * 16 + r16) * 64 + kk + q4 * 8];
      __builtin_amdgcn_s_setprio(1);
#pragma unroll
      for (int m = 0; m < 4; ++m)
#pragma unroll
        for (int n = 0; n < 4; ++n)
          acc[m][n] = __builtin_amdgcn_mfma_f32_16x16x32_bf16(af[m], bfv[n], acc[m][n], 0, 0, 0);
      __builtin_amdgcn_s_setprio(0);
    }
    __syncthreads();
  }
#pragma unroll
  for (int n = 0; n < 4; ++n) {
    int gc = tn * 128 + wn * 64 + n * 16 + r16;
    float bv = bias[gc];
#pragma unroll
    for (int m = 0; m < 4; ++m) {
      int gr0 = tm * 128 + wm * 64 + m * 16 + q4 * 4;
#pragma unroll
      for (int j = 0; j < 4; ++j) {
        float v = acc[m][n][j] + bv;
        if (OUTF32)
          ((float*)Cout)[(size_t)(gr0 + j) * N + gc] = v;
        else
          ((u16*)Cout)[(size_t)(gr0 + j) * N + gc] = f2bf(v);
      }
    }
  }
}

// ---------------- causal flash attention v5: uniform 17-tile work units ----------------
// 512 blocks: xcd=b&7, rr=b>>3, p=rr&7, h01=(rr>>3)&1, g=rr>>4; bh=g*8+xcd.
// Pair (qtL=15-p, qtS=p): total 34 KV-tiles, split 17/17 along concatenated KV stream:
//   h01=0: qtL, kv tiles [0,17)          -> partial slot 0
//   h01=1: qtL, kv tiles [17,32-2p)      -> partial slot 1,  then qtS full -> final O
// Every block = exactly 17 tiles; balance is placement-independent.
__global__ __launch_bounds__(256, 2) void attn_kernel(const u16* __restrict__ Q, const u16* __restrict__ K,
                                                      const u16* __restrict__ VT, u16* __restrict__ O,
                                                      float* __restrict__ pAO, float* __restrict__ pML) {
  __shared__ u16 Kl[2][KVB * 128];
  __shared__ u16 Vl[2][128 * KVB];
  __shared__ u16 Pl[4][32 * 64];
  const int t = threadIdx.x;
  const int lane = t & 63, w = t >> 6;
  const int r16 = lane & 15, q4 = lane >> 4;
  const int b = blockIdx.x;
  const int xcd = b & 7, rr = b >> 3;
  const int p = rr & 7, h01 = (rr >> 3) & 1, g = rr >> 4;
  const int bh = g * 8 + xcd;
  const int bb = bh >> 4, h = bh & 15;
  const size_t headoff = (size_t)bb * S_ * HID_ + (size_t)h * 128;
  const u16* Qb = Q + headoff;
  const u16* Kb = K + headoff;
  const u16* VTb = VT + (size_t)bh * 128 * S_;
  u16* Ob = O + headoff;
  const int qtL = 15 - p, ntL = 32 - 2 * p;
  const int nseg = h01 ? 2 : 1;

  for (int seg = 0; seg < nseg; ++seg) {
    int qt, t0, t1, mode;   // mode 0/1: partial slot; 2: final
    if (!h01)          { qt = qtL; t0 = 0;  t1 = 17;        mode = 0; }
    else if (seg == 0) { qt = qtL; t0 = 17; t1 = ntL;       mode = 1; }
    else               { qt = p;   t0 = 0;  t1 = 2 * p + 2; mode = 2; }
    const int qrow0 = qt * 128 + w * 32;

    short8 qf[2][4];
#pragma unroll
    for (int m = 0; m < 2; ++m)
#pragma unroll
      for (int dk = 0; dk < 4; ++dk)
        qf[m][dk] = *(const short8*)&Qb[(size_t)(qrow0 + m * 16 + r16) * HID_ + dk * 32 + q4 * 8];

    f32x4 ao[2][8];
    float mr[2][4], lr[2][4];
#pragma unroll
    for (int m = 0; m < 2; ++m) {
#pragma unroll
      for (int dn = 0; dn < 8; ++dn) ao[m][dn] = (f32x4){0.f, 0.f, 0.f, 0.f};
#pragma unroll
      for (int j = 0; j < 4; ++j) { mr[m][j] = -1e30f; lr[m][j] = 0.f; }
    }

    auto stage = [&](int buf, int kvbase) {
#pragma unroll
      for (int c = 0; c < 4; ++c) {
        int s = c * 256 + t;
        int row = s >> 4;
        int chs = (s & 15) ^ (row & 7);
        gload16(&Kb[(size_t)(kvbase + row) * HID_ + chs * 8], (char*)Kl[buf] + s * 16);
      }
#pragma unroll
      for (int c = 0; c < 4; ++c) {
        int s = c * 256 + t;
        int row = s >> 3;
        int chs = (s & 7) ^ (row & 7);
        gload16(&VTb[(size_t)row * S_ + kvbase + chs * 8], (char*)Vl[buf] + s * 16);
      }
    };

    stage(0, t0 * KVB);
    __syncthreads();

    for (int ti = t0; ti < t1; ++ti) {
      const int buf = (ti - t0) & 1;
      const int kv0 = ti * KVB;
      if (ti + 1 < t1) stage(buf ^ 1, (ti + 1) * KVB);

      if (kv0 <= qrow0 + 31) {
        // ---- QK^T ----
        f32x4 sc[2][4];
#pragma unroll
        for (int m = 0; m < 2; ++m)
#pragma unroll
          for (int n = 0; n < 4; ++n) sc[m][n] = (f32x4){0.f, 0.f, 0.f, 0.f};
#pragma unroll
        for (int dk = 0; dk < 4; ++dk) {
          short8 kf[4];
#pragma unroll
          for (int n = 0; n < 4; ++n) {
            int kr = n * 16 + r16;
            int ba = (kr * 256 + dk * 64 + q4 * 16) ^ ((kr & 7) << 4);
            kf[n] = *(const short8*)((const char*)Kl[buf] + ba);
          }
          __builtin_amdgcn_s_setprio(1);
#pragma unroll
          for (int m = 0; m < 2; ++m)
#pragma unroll
            for (int n = 0; n < 4; ++n)
              sc[m][n] = __builtin_amdgcn_mfma_f32_16x16x32_bf16(qf[m][dk], kf[n], sc[m][n], 0, 0, 0);
          __builtin_amdgcn_s_setprio(0);
        }
        // ---- scale + causal mask ----
        const float SCALE = 0.08838834764831845f;
        const bool need_mask = (kv0 + 63 > qrow0);
#pragma unroll
        for (int m = 0; m < 2; ++m)
#pragma unroll
          for (int n = 0; n < 4; ++n)
#pragma unroll
            for (int j = 0; j < 4; ++j) {
              float sv = sc[m][n][j] * SCALE;
              if (need_mask) {
                int row = qrow0 + m * 16 + q4 * 4 + j;
                int col = kv0 + n * 16 + r16;
                if (col > row) sv = -1e30f;
              }
              sc[m][n][j] = sv;
            }
        // ---- online softmax with defer-max ----
        float tmax[2][4];
#pragma unroll
        for (int m = 0; m < 2; ++m)
#pragma unroll
          for (int j = 0; j < 4; ++j) {
            float tm = fmaxf(fmaxf(sc[m][0][j], sc[m][1][j]), fmaxf(sc[m][2][j], sc[m][3][j]));
            tm = fmaxf(tm, __shfl_xor(tm, 1));
            tm = fmaxf(tm, __shfl_xor(tm, 2));
            tm = fmaxf(tm, __shfl_xor(tm, 4));
            tm = fmaxf(tm, __shfl_xor(tm, 8));
            tmax[m][j] = tm;
          }
        float growth = -1e30f;
#pragma unroll
        for (int m = 0; m < 2; ++m)
#pragma unroll
          for (int j = 0; j < 4; ++j) growth = fmaxf(growth, tmax[m][j] - mr[m][j]);
        if (!__all(growth <= 8.0f)) {
#pragma unroll
          for (int m = 0; m < 2; ++m)
#pragma unroll
            for (int j = 0; j < 4; ++j) {
              float mnew = fmaxf(mr[m][j], tmax[m][j]);
              float fsc = __expf(mr[m][j] - mnew);
              lr[m][j] *= fsc;
              mr[m][j] = mnew;
#pragma unroll
              for (int dn = 0; dn < 8; ++dn) ao[m][dn][j] *= fsc;
            }
        }
#pragma unroll
        for (int m = 0; m < 2; ++m)
#pragma unroll
          for (int j = 0; j < 4; ++j) {
            float ps = 0.f;
#pragma unroll
            for (int n = 0; n < 4; ++n) {
              float pv = __expf(sc[m][n][j] - mr[m][j]);
              sc[m][n][j] = pv;
              ps += pv;
            }
            ps += __shfl_xor(ps, 1);
            ps += __shfl_xor(ps, 2);
            ps += __shfl_xor(ps, 4);
            ps += __shfl_xor(ps, 8);
            lr[m][j] += ps;
          }
        // ---- P -> LDS (per-wave, XOR-swizzled) ----
        u16* Pw = &Pl[w][0];
#pragma unroll
        for (int m = 0; m < 2; ++m)
#pragma unroll
          for (int n = 0; n < 4; ++n)
#pragma unroll
            for (int j = 0; j < 4; ++j) {
              int row = m * 16 + q4 * 4 + j;
              int col = n * 16 + r16;
              int ba = (row * 128 + col * 2) ^ ((row & 7) << 4);
              *(u16*)((char*)Pw + ba) = f2bf(sc[m][n][j]);
            }
        // ---- PV ----
#pragma unroll
        for (int ck = 0; ck < 2; ++ck) {
          short8 pa[2];
#pragma unroll
          for (int m = 0; m < 2; ++m) {
            int row = m * 16 + r16;
            int ba = (row * 128 + ck * 64 + q4 * 16) ^ ((row & 7) << 4);
            pa[m] = *(const short8*)((const char*)Pw + ba);
          }
          __builtin_amdgcn_s_setprio(1);
#pragma unroll
          for (int dn = 0; dn < 8; ++dn) {
            int dr = dn * 16 + r16;
            int ba = (dr * 128 + ck * 64 + q4 * 16) ^ ((dr & 7) << 4);
            short8 vf = *(const short8*)((const char*)Vl[buf] + ba);
#pragma unroll
            for (int m = 0; m < 2; ++m)
              ao[m][dn] = __builtin_amdgcn_mfma_f32_16x16x32_bf16(pa[m], vf, ao[m][dn], 0, 0, 0);
          }
          __builtin_amdgcn_s_setprio(0);
        }
      }
      __syncthreads();   // drains vmcnt: next tile's K/V DMA complete; buffers safe to swap
    }

    // ---- per-segment writeout ----
    if (mode == 2) {
#pragma unroll
      for (int m = 0; m < 2; ++m)
#pragma unroll
        for (int j = 0; j < 4; ++j) {
          float inv = 1.f / lr[m][j];
          int row = qrow0 + m * 16 + q4 * 4 + j;
#pragma unroll
          for (int dn = 0; dn < 8; ++dn)
            Ob[(size_t)row * HID_ + dn * 16 + r16] = f2bf(ao[m][dn][j] * inv);
        }
    } else {
      const int slot = (bh * 8 + p) * 2 + mode;
      float* ao_s = pAO + (size_t)slot * (128 * 128);
      float* ml_s = pML + (size_t)slot * (128 * 2);
#pragma unroll
      for (int m = 0; m < 2; ++m)
#pragma unroll
        for (int j = 0; j < 4; ++j) {
          int row = w * 32 + m * 16 + q4 * 4 + j;
#pragma unroll
          for (int dn = 0; dn < 8; ++dn)
            ao_s[row * 128 + dn * 16 + r16] = ao[m][dn][j];
          if (r16 == 0) { ml_s[row * 2] = mr[m][j]; ml_s[row * 2 + 1] = lr[m][j]; }
        }
    }
  }
}

// ---------------- combine split-KV partials for long q-tiles ----------------
__global__ __launch_bounds__(256) void attn_combine(const float* __restrict__ pAO,
                                                    const float* __restrict__ pML,
                                                    u16* __restrict__ O) {
  const int u = blockIdx.x;        // 256 units = 32 bh x 8 pairs
  const int p = u & 7, bh = u >> 3;
  const int qtL = 15 - p;
  const int bb = bh >> 4, h = bh & 15;
  u16* Ob = O + (size_t)bb * S_ * HID_ + (size_t)h * 128;
  const float* a0 = pAO + (size_t)(u * 2) * (128 * 128);
  const float* a1 = a0 + 128 * 128;
  const float* ml0 = pML + (size_t)(u * 2) * (128 * 2);
  const float* ml1 = ml0 + 128 * 2;
  const int t = threadIdx.x;
  const int row = t >> 1, half = t & 1;
  float m0 = ml0[row * 2], l0 = ml0[row * 2 + 1];
  float m1 = ml1[row * 2], l1 = ml1[row * 2 + 1];
  float M = fmaxf(m0, m1);
  float w0 = __expf(m0 - M), w1 = __expf(m1 - M);
  float inv = 1.f / (l0 * w0 + l1 * w1);
  const int gr = qtL * 128 + row;
  const int c0 = half * 64;
#pragma unroll
  for (int c = 0; c < 64; c += 4) {
    f32x4 v0 = *(const f32x4*)&a0[row * 128 + c0 + c];
    f32x4 v1 = *(const f32x4*)&a1[row * 128 + c0 + c];
    u16x4 o;
#pragma unroll
    for (int j = 0; j < 4; ++j) o[j] = f2bf((v0[j] * w0 + v1[j] * w1) * inv);
    *(u16x4*)&Ob[(size_t)gr * HID_ + c0 + c] = o;
  }
}

// ---------------- host launch ----------------
extern "C" void kernel_launch(void* const* d_in, const int* in_sizes, int n_in,
                              void* d_out, int out_size, void* d_ws, size_t ws_size,
                              hipStream_t stream) {
  (void)in_sizes; (void)n_in; (void)out_size; (void)ws_size;
  const float* x     = (const float*)d_in[0];
  const float* W_dkv = (const float*)d_in[2];
  const float* b_dkv = (const float*)d_in[3];
  const float* W_uk  = (const float*)d_in[4];
  const float* b_uk  = (const float*)d_in[5];
  const float* W_uv  = (const float*)d_in[6];
  const float* b_uv  = (const float*)d_in[7];
  const float* W_dq  = (const float*)d_in[8];
  const float* b_dq  = (const float*)d_in[9];
  const float* W_uq  = (const float*)d_in[10];
  const float* b_uq  = (const float*)d_in[11];
  const float* W_o   = (const float*)d_in[12];
  const float* b_o   = (const float*)d_in[13];
  float* out = (float*)d_out;

  char* ws = (char*)d_ws;
  size_t off = 0;
  auto carve = [&](size_t bytes) { void* p = ws + off; off += (bytes + 255) & ~(size_t)255; return p; };
  u16* xb    = (u16*)carve((size_t)BS_ * 2048 * 2);   // reused as VT after q1 GEMM
  u16* WdkvT = (u16*)carve((size_t)512 * 2048 * 2);
  u16* WukT  = (u16*)carve((size_t)2048 * 512 * 2);
  u16* WuvT  = (u16*)carve((size_t)2048 * 512 * 2);
  u16* WdqT  = (u16*)carve((size_t)1536 * 2048 * 2);
  u16* WuqT  = (u16*)carve((size_t)2048 * 1536 * 2);
  u16* WoT   = (u16*)carve((size_t)2048 * 2048 * 2);
  u16* kvb   = (u16*)carve((size_t)BS_ * 512 * 2);
  u16* q1b   = (u16*)carve((size_t)BS_ * 1536 * 2);
  u16* qb    = (u16*)carve((size_t)BS_ * 2048 * 2);
  u16* kb    = (u16*)carve((size_t)BS_ * 2048 * 2);
  u16* vb    = (u16*)carve((size_t)BS_ * 2048 * 2);
  u16* aob   = (u16*)carve((size_t)BS_ * 2048 * 2);
  float* ct  = (float*)carve((size_t)2048 * 64 * 4);
  float* st  = (float*)carve((size_t)2048 * 64 * 4);
  float* pML = (float*)carve((size_t)512 * 128 * 2 * 4);
  u16* VT    = xb;            // xb dead after q1 GEMM
  float* pAO = out;           // 512*128*128*4 == 4096*2048*4 exactly; out written only by final GEMM

  conv_f2b<<<dim3(BS_ * 2048 / 4 / 256), 256, 0, stream>>>(x, xb, BS_ * 2048 / 4);
  transpose_conv<<<dim3(512 / 64, 2048 / 64), 256, 0, stream>>>(W_dkv, WdkvT, 2048, 512);
  transpose_conv<<<dim3(2048 / 64, 512 / 64), 256, 0, stream>>>(W_uk, WukT, 512, 2048);
  transpose_conv<<<dim3(2048 / 64, 512 / 64), 256, 0, stream>>>(W_uv, WuvT, 512, 2048);
  transpose_conv<<<dim3(1536 / 64, 2048 / 64), 256, 0, stream>>>(W_dq, WdqT, 2048, 1536);
  transpose_conv<<<dim3(2048 / 64, 1536 / 64), 256, 0, stream>>>(W_uq, WuqT, 1536, 2048);
  transpose_conv<<<dim3(2048 / 64, 2048 / 64), 256, 0, stream>>>(W_o, WoT, 2048, 2048);
  rope_table<<<dim3(512), 256, 0, stream>>>(ct, st);

  gemm_bt<0><<<dim3(512 / 128, BS_ / 128), 256, 0, stream>>>(xb, WdkvT, b_dkv, kvb, BS_, 512, 2048);
  gemm_bt<0><<<dim3(1536 / 128, BS_ / 128), 256, 0, stream>>>(xb, WdqT, b_dq, q1b, BS_, 1536, 2048);
  // xb dead from here on
  gemm_bt<0><<<dim3(2048 / 128, BS_ / 128), 256, 0, stream>>>(kvb, WukT, b_uk, kb, BS_, 2048, 512);
  gemm_bt<0><<<dim3(2048 / 128, BS_ / 128), 256, 0, stream>>>(kvb, WuvT, b_uv, vb, BS_, 2048, 512);
  gemm_bt<0><<<dim3(2048 / 128, BS_ / 128), 256, 0, stream>>>(q1b, WuqT, b_uq, qb, BS_, 2048, 1536);

  rope_apply<<<dim3(BS_ * 1024 / 256), 256, 0, stream>>>((u32*)qb, ct, st);
  rope_apply<<<dim3(BS_ * 1024 / 256), 256, 0, stream>>>((u32*)kb, ct, st);
  vtrans<<<dim3(S_ / 64, 32), 256, 0, stream>>>(vb, VT);

  attn_kernel<<<dim3(512), 256, 0, stream>>>(qb, kb, VT, aob, pAO, pML);
  attn_combine<<<dim3(256), 256, 0, stream>>>(pAO, pML, aob);

  gemm_bt<1><<<dim3(2048 / 128, BS_ / 128), 256, 0, stream>>>(aob, WoT, b_o, out, BS_, 2048, 2048);
}

// Round 6
// 353.476 us; speedup vs baseline: 1.2021x; 1.2021x over previous
//
#include <hip/hip_runtime.h>
#include <stdint.h>

typedef unsigned short u16;
typedef uint32_t u32;
typedef __attribute__((ext_vector_type(8))) short short8;
typedef __attribute__((ext_vector_type(4))) float f32x4;
typedef __attribute__((ext_vector_type(4))) u32 u32x4;
typedef __attribute__((ext_vector_type(2))) u32 u32x2;
typedef __attribute__((ext_vector_type(4))) unsigned short u16x4;

#define BS_ 4096   // B*S rows
#define S_ 2048
#define HID_ 2048
#define KVB 64

__device__ __forceinline__ float bf2f(u16 u) { union { u32 i; float f; } v; v.i = ((u32)u) << 16; return v.f; }
__device__ __forceinline__ u16 f2bf(float f) {
  union { float f; u32 i; } v; v.f = f;
  u32 r = v.i + 0x7fffu + ((v.i >> 16) & 1u);
  return (u16)(r >> 16);
}

__device__ __forceinline__ void gload16(const void* gsrc, void* ldst) {
  __builtin_amdgcn_global_load_lds(
      (const __attribute__((address_space(1))) void*)gsrc,
      (__attribute__((address_space(3))) void*)ldst, 16, 0, 0);
}

// ---------------- elementwise convert fp32 -> bf16 ----------------
__global__ __launch_bounds__(256) void conv_f2b(const float* __restrict__ in, u16* __restrict__ out, int n4) {
  int i = blockIdx.x * 256 + threadIdx.x;
  if (i < n4) {
    float4 v = ((const float4*)in)[i];
    u16x4 o;
    o.x = f2bf(v.x); o.y = f2bf(v.y); o.z = f2bf(v.z); o.w = f2bf(v.w);
    ((u16x4*)out)[i] = o;
  }
}

// ---------------- transpose + convert: W[K][N] fp32 -> WT[N][K] bf16 ----------------
__global__ __launch_bounds__(256) void transpose_conv(const float* __restrict__ W, u16* __restrict__ WT,
                                                      int K, int N) {
  __shared__ float tile[64][65];
  const int t = threadIdx.x;
  const int kb = blockIdx.y * 64, nb = blockIdx.x * 64;
#pragma unroll
  for (int c = 0; c < 4; ++c) {
    int idx = c * 256 + t;
    int row = idx >> 4;
    int col4 = (idx & 15) * 4;
    float4 v = *(const float4*)&W[(size_t)(kb + row) * N + nb + col4];
    tile[row][col4 + 0] = v.x; tile[row][col4 + 1] = v.y;
    tile[row][col4 + 2] = v.z; tile[row][col4 + 3] = v.w;
  }
  __syncthreads();
#pragma unroll
  for (int c = 0; c < 4; ++c) {
    int idx = c * 256 + t;
    int n = idx >> 4;
    int k4 = (idx & 15) * 4;
    u16x4 o;
    o.x = f2bf(tile[k4 + 0][n]); o.y = f2bf(tile[k4 + 1][n]);
    o.z = f2bf(tile[k4 + 2][n]); o.w = f2bf(tile[k4 + 3][n]);
    *(u16x4*)&WT[(size_t)(nb + n) * K + kb + k4] = o;
  }
}

// ---------------- V transpose: vb[b][s][h*128+d] -> VT[(b*16+h)][d][s] ----------------
__global__ __launch_bounds__(256) void vtrans(const u16* __restrict__ Vin, u16* __restrict__ VT) {
  __shared__ u16 tile[64][136];
  const int t = threadIdx.x;
  const int st0 = blockIdx.x * 64;
  const int bh = blockIdx.y;
  const int bb = bh >> 4, h = bh & 15;
  const u16* src = Vin + (size_t)bb * S_ * HID_ + (size_t)h * 128;
  u16* dst = VT + (size_t)bh * 128 * S_;
#pragma unroll
  for (int c = 0; c < 4; ++c) {
    int idx = c * 256 + t;
    int s = idx >> 4, ch = idx & 15;
    short8 v = *(const short8*)&src[(size_t)(st0 + s) * HID_ + ch * 8];
    *(short8*)&tile[s][ch * 8] = v;
  }
  __syncthreads();
#pragma unroll
  for (int c = 0; c < 4; ++c) {
    int idx = c * 256 + t;
    int d = idx >> 3, ch = idx & 7;
    short8 o;
#pragma unroll
    for (int j = 0; j < 8; ++j) o[j] = tile[ch * 8 + j][d];
    *(short8*)&dst[(size_t)d * S_ + st0 + ch * 8] = o;
  }
}

// ---------------- RoPE table ----------------
__global__ __launch_bounds__(256) void rope_table(float* __restrict__ ct, float* __restrict__ st) {
  int idx = blockIdx.x * 256 + threadIdx.x;
  int pos = idx >> 6, i = idx & 63;
  float inv = powf(10000.f, -(float)i / 64.f);
  float a = (float)pos * inv;
  ct[idx] = cosf(a);
  st[idx] = sinf(a);
}

// ---------------- RoPE apply ----------------
__global__ __launch_bounds__(256) void rope_apply(u32* __restrict__ buf, const float* __restrict__ ct,
                                                  const float* __restrict__ st) {
  int idx = blockIdx.x * 256 + threadIdx.x;
  int s = (idx >> 10) & 2047;
  int i = idx & 63;
  u32 v = buf[idx];
  float x1 = bf2f((u16)(v & 0xffff)), x2 = bf2f((u16)(v >> 16));
  float c = ct[s * 64 + i], sn = st[s * 64 + i];
  float o1 = x1 * c - x2 * sn;
  float o2 = x1 * sn + x2 * c;
  buf[idx] = (u32)f2bf(o1) | ((u32)f2bf(o2) << 16);
}

// ---------------- GEMM (m97-structure + XCD-aware block swizzle) ----------------
template <int OUTF32>
__global__ __launch_bounds__(256) void gemm_bt(const u16* __restrict__ A, const u16* __restrict__ BT,
                                               const float* __restrict__ bias, void* __restrict__ Cout,
                                               int M, int N, int K) {
  __shared__ u16 As[128 * 64];
  __shared__ u16 Bs[128 * 64];
  const int t = threadIdx.x;
  const int lane = t & 63, wave = t >> 6;
  const int wm = wave >> 1, wn = wave & 1;
  const int gx = gridDim.x;
  const int nwg = gx * gridDim.y;
  const int flat = blockIdx.y * gx + blockIdx.x;
  const int swz = (flat & 7) * (nwg >> 3) + (flat >> 3);
  const int tn = swz % gx, tm = swz / gx;
  const int r16 = lane & 15, q4 = lane >> 4;

  f32x4 acc[4][4];
#pragma unroll
  for (int m = 0; m < 4; ++m)
#pragma unroll
    for (int n = 0; n < 4; ++n) acc[m][n] = (f32x4){0.f, 0.f, 0.f, 0.f};

  for (int kt = 0; kt < K; kt += 64) {
#pragma unroll
    for (int c = 0; c < 4; ++c) {
      int idx = c * 256 + t;
      int row = idx >> 3, ch = idx & 7;
      gload16(&A[(size_t)(tm * 128 + row) * K + kt + ch * 8], (char*)As + idx * 16);
      gload16(&BT[(size_t)(tn * 128 + row) * K + kt + ch * 8], (char*)Bs + idx * 16);
    }
    __syncthreads();
#pragma unroll
    for (int kk = 0; kk < 64; kk += 32) {
      short8 af[4], bfv[4];
#pragma unroll
      for (int m = 0; m < 4; ++m)
        af[m] = *(const short8*)&As[(wm * 64 + m * 16 + r16) * 64 + kk + q4 * 8];
#pragma unroll
      for (int n = 0; n < 4; ++n)
        bfv[n] = *(const short8*)&Bs[(wn * 64 + n * 16 + r16) * 64 + kk + q4 * 8];
      __builtin_amdgcn_s_setprio(1);
#pragma unroll
      for (int m = 0; m < 4; ++m)
#pragma unroll
        for (int n = 0; n < 4; ++n)
          acc[m][n] = __builtin_amdgcn_mfma_f32_16x16x32_bf16(af[m], bfv[n], acc[m][n], 0, 0, 0);
      __builtin_amdgcn_s_setprio(0);
    }
    __syncthreads();
  }
#pragma unroll
  for (int n = 0; n < 4; ++n) {
    int gc = tn * 128 + wn * 64 + n * 16 + r16;
    float bv = bias[gc];
#pragma unroll
    for (int m = 0; m < 4; ++m) {
      int gr0 = tm * 128 + wm * 64 + m * 16 + q4 * 4;
#pragma unroll
      for (int j = 0; j < 4; ++j) {
        float v = acc[m][n][j] + bv;
        if (OUTF32)
          ((float*)Cout)[(size_t)(gr0 + j) * N + gc] = v;
        else
          ((u16*)Cout)[(size_t)(gr0 + j) * N + gc] = f2bf(v);
      }
    }
  }
}

// ---------------- causal flash attention v6: swapped QK^T, paired q-tiles ----------------
// 512 blocks: xcd=b&7, u=b>>3, p=u&15, g4=u>>4; bh=g4*8+xcd.
// Each block: segment 0 = q-tile p (p+1 KV tiles), segment 1 = q-tile 31-p (32-p tiles):
// exactly 33 KV-tile computations per block -- placement-independent balance, no partials.
// Block: 64 q-rows/segment, 4 waves x 16 rows. Swapped mfma(K,Q): lane owns one q-col,
// kv lives in regs -> softmax = 15 VALU + 2 shfl; P packed via v_cvt_pk_bf16_f32.
__global__ __launch_bounds__(256, 2) void attn_kernel(const u16* __restrict__ Q, const u16* __restrict__ K,
                                                      const u16* __restrict__ VT, u16* __restrict__ O) {
  __shared__ u16 Kl[2][KVB * 128];   // 16KB each, [kv][d] rows 256B
  __shared__ u16 Vl[2][128 * KVB];   // 16KB each, [d][kv] rows 128B
  __shared__ u16 Pl[4][16 * 64];     // per-wave P [q][kv], 2KB each
  const int t = threadIdx.x;
  const int lane = t & 63, w = t >> 6;
  const int r16 = lane & 15, q4 = lane >> 4;
  const int b = blockIdx.x;
  const int xcd = b & 7, u = b >> 3;
  const int p = u & 15, g4 = u >> 4;
  const int bh = g4 * 8 + xcd;
  const int bb = bh >> 4, h = bh & 15;
  const size_t headoff = (size_t)bb * S_ * HID_ + (size_t)h * 128;
  const u16* Qb = Q + headoff;
  const u16* Kb = K + headoff;
  const u16* VTb = VT + (size_t)bh * 128 * S_;
  u16* Ob = O + headoff;

  auto stage = [&](int buf, int kvbase) {
#pragma unroll
    for (int c = 0; c < 4; ++c) {
      int s = c * 256 + t;
      int row = s >> 4;
      int chs = (s & 15) ^ (row & 7);
      gload16(&Kb[(size_t)(kvbase + row) * HID_ + chs * 8], (char*)Kl[buf] + s * 16);
    }
#pragma unroll
    for (int c = 0; c < 4; ++c) {
      int s = c * 256 + t;
      int row = s >> 3;
      int chs = (s & 7) ^ (row & 7);
      gload16(&VTb[(size_t)row * S_ + kvbase + chs * 8], (char*)Vl[buf] + s * 16);
    }
  };

  u16* Pw = &Pl[w][0];
  const float SCALE = 0.08838834764831845f;

#pragma unroll
  for (int seg = 0; seg < 2; ++seg) {
    const int qt = seg ? (31 - p) : p;
    const int nt = qt + 1;               // KV tiles 0..qt (kv0 <= qrow0 always)
    const int qrow0 = qt * 64 + w * 16;
    const int q = qrow0 + r16;           // this lane's q-row

    short8 qf[4];
#pragma unroll
    for (int dk = 0; dk < 4; ++dk)
      qf[dk] = *(const short8*)&Qb[(size_t)q * HID_ + dk * 32 + q4 * 8];

    f32x4 ao[8];
#pragma unroll
    for (int dn = 0; dn < 8; ++dn) ao[dn] = (f32x4){0.f, 0.f, 0.f, 0.f};
    float mr = -1e30f, lr = 0.f;

    stage(0, 0);
    __syncthreads();

    for (int ti = 0; ti < nt; ++ti) {
      const int buf = ti & 1;
      const int kv0 = ti * KVB;
      if (ti + 1 < nt) stage(buf ^ 1, kv0 + KVB);

      // ---- QK^T swapped: sc[n] = S^T block, col=q(lane), row=kv(q4*4+j within 16n) ----
      f32x4 sc[4];
#pragma unroll
      for (int n = 0; n < 4; ++n) sc[n] = (f32x4){0.f, 0.f, 0.f, 0.f};
#pragma unroll
      for (int dk = 0; dk < 4; ++dk) {
        short8 kf[4];
#pragma unroll
        for (int n = 0; n < 4; ++n) {
          int kr = n * 16 + r16;
          int ba = (kr * 256 + dk * 64 + q4 * 16) ^ ((kr & 7) << 4);
          kf[n] = *(const short8*)((const char*)Kl[buf] + ba);
        }
        __builtin_amdgcn_s_setprio(1);
#pragma unroll
        for (int n = 0; n < 4; ++n)
          sc[n] = __builtin_amdgcn_mfma_f32_16x16x32_bf16(kf[n], qf[dk], sc[n], 0, 0, 0);
        __builtin_amdgcn_s_setprio(0);
      }
      // ---- scale + causal mask (kv > q masked) ----
      const bool nm = (kv0 + 63 > qrow0);
#pragma unroll
      for (int n = 0; n < 4; ++n)
#pragma unroll
        for (int j = 0; j < 4; ++j) {
          float sv = sc[n][j] * SCALE;
          if (nm) {
            int kv = kv0 + n * 16 + q4 * 4 + j;
            if (kv > q) sv = -1e30f;
          }
          sc[n][j] = sv;
        }
      // ---- online softmax: 15 local fmax + 2 shfl ----
      float tm = sc[0][0];
#pragma unroll
      for (int n = 0; n < 4; ++n)
#pragma unroll
        for (int j = 0; j < 4; ++j) tm = fmaxf(tm, sc[n][j]);
      tm = fmaxf(tm, __shfl_xor(tm, 16));
      tm = fmaxf(tm, __shfl_xor(tm, 32));
      if (!__all(tm - mr <= 8.0f)) {
        float mnew = fmaxf(mr, tm);
        float fsc = __expf(mr - mnew);
        lr *= fsc; mr = mnew;
#pragma unroll
        for (int dn = 0; dn < 8; ++dn) ao[dn] *= fsc;
      }
      float ps = 0.f;
#pragma unroll
      for (int n = 0; n < 4; ++n)
#pragma unroll
        for (int j = 0; j < 4; ++j) {
          float pv = __expf(sc[n][j] - mr);
          sc[n][j] = pv;
          ps += pv;
        }
      ps += __shfl_xor(ps, 16);
      ps += __shfl_xor(ps, 32);
      lr += ps;
      // ---- P -> LDS: cvt_pk pairs, 4x ds_write_b64 ----
#pragma unroll
      for (int n = 0; n < 4; ++n) {
        u32 lo, hi;
        asm("v_cvt_pk_bf16_f32 %0, %1, %2" : "=v"(lo) : "v"(sc[n][0]), "v"(sc[n][1]));
        asm("v_cvt_pk_bf16_f32 %0, %1, %2" : "=v"(hi) : "v"(sc[n][2]), "v"(sc[n][3]));
        u32x2 pr; pr.x = lo; pr.y = hi;
        int ba = (r16 * 128 + n * 32 + q4 * 8) ^ ((r16 & 7) << 4);
        *(u32x2*)((char*)Pw + ba) = pr;
      }
      // ---- PV: O^T = mfma(A=V^T-frag, B=P^T-frag) ----
#pragma unroll
      for (int s = 0; s < 2; ++s) {
        int bp = (r16 * 128 + s * 64 + q4 * 16) ^ ((r16 & 7) << 4);
        short8 pb = *(const short8*)((const char*)Pw + bp);
        __builtin_amdgcn_s_setprio(1);
#pragma unroll
        for (int dn = 0; dn < 8; ++dn) {
          int dr = dn * 16 + r16;
          int bv = (dr * 128 + s * 64 + q4 * 16) ^ ((dr & 7) << 4);
          short8 vf = *(const short8*)((const char*)Vl[buf] + bv);
          ao[dn] = __builtin_amdgcn_mfma_f32_16x16x32_bf16(vf, pb, ao[dn], 0, 0, 0);
        }
        __builtin_amdgcn_s_setprio(0);
      }
      __syncthreads();   // drains vmcnt: next tile staged; buffers safe
    }

    // ---- epilogue: O[q][d], contiguous-d u16x4 stores ----
    float inv = 1.f / lr;
#pragma unroll
    for (int dn = 0; dn < 8; ++dn) {
      u16x4 o;
#pragma unroll
      for (int j = 0; j < 4; ++j) o[j] = f2bf(ao[dn][j] * inv);
      *(u16x4*)&Ob[(size_t)q * HID_ + dn * 16 + q4 * 4] = o;
    }
    __syncthreads();   // segment boundary before restaging Kl[0]/Vl[0]
  }
}

// ---------------- host launch ----------------
extern "C" void kernel_launch(void* const* d_in, const int* in_sizes, int n_in,
                              void* d_out, int out_size, void* d_ws, size_t ws_size,
                              hipStream_t stream) {
  (void)in_sizes; (void)n_in; (void)out_size; (void)ws_size;
  const float* x     = (const float*)d_in[0];
  const float* W_dkv = (const float*)d_in[2];
  const float* b_dkv = (const float*)d_in[3];
  const float* W_uk  = (const float*)d_in[4];
  const float* b_uk  = (const float*)d_in[5];
  const float* W_uv  = (const float*)d_in[6];
  const float* b_uv  = (const float*)d_in[7];
  const float* W_dq  = (const float*)d_in[8];
  const float* b_dq  = (const float*)d_in[9];
  const float* W_uq  = (const float*)d_in[10];
  const float* b_uq  = (const float*)d_in[11];
  const float* W_o   = (const float*)d_in[12];
  const float* b_o   = (const float*)d_in[13];
  float* out = (float*)d_out;

  char* ws = (char*)d_ws;
  size_t off = 0;
  auto carve = [&](size_t bytes) { void* p = ws + off; off += (bytes + 255) & ~(size_t)255; return p; };
  u16* xb    = (u16*)carve((size_t)BS_ * 2048 * 2);   // reused as VT after q1 GEMM
  u16* WdkvT = (u16*)carve((size_t)512 * 2048 * 2);
  u16* WukT  = (u16*)carve((size_t)2048 * 512 * 2);
  u16* WuvT  = (u16*)carve((size_t)2048 * 512 * 2);
  u16* WdqT  = (u16*)carve((size_t)1536 * 2048 * 2);
  u16* WuqT  = (u16*)carve((size_t)2048 * 1536 * 2);
  u16* WoT   = (u16*)carve((size_t)2048 * 2048 * 2);
  u16* kvb   = (u16*)carve((size_t)BS_ * 512 * 2);
  u16* q1b   = (u16*)carve((size_t)BS_ * 1536 * 2);
  u16* qb    = (u16*)carve((size_t)BS_ * 2048 * 2);
  u16* kb    = (u16*)carve((size_t)BS_ * 2048 * 2);
  u16* vb    = (u16*)carve((size_t)BS_ * 2048 * 2);
  u16* aob   = (u16*)carve((size_t)BS_ * 2048 * 2);
  float* ct  = (float*)carve((size_t)2048 * 64 * 4);
  float* st  = (float*)carve((size_t)2048 * 64 * 4);
  u16* VT    = xb;            // xb dead after q1 GEMM

  conv_f2b<<<dim3(BS_ * 2048 / 4 / 256), 256, 0, stream>>>(x, xb, BS_ * 2048 / 4);
  transpose_conv<<<dim3(512 / 64, 2048 / 64), 256, 0, stream>>>(W_dkv, WdkvT, 2048, 512);
  transpose_conv<<<dim3(2048 / 64, 512 / 64), 256, 0, stream>>>(W_uk, WukT, 512, 2048);
  transpose_conv<<<dim3(2048 / 64, 512 / 64), 256, 0, stream>>>(W_uv, WuvT, 512, 2048);
  transpose_conv<<<dim3(1536 / 64, 2048 / 64), 256, 0, stream>>>(W_dq, WdqT, 2048, 1536);
  transpose_conv<<<dim3(2048 / 64, 1536 / 64), 256, 0, stream>>>(W_uq, WuqT, 1536, 2048);
  transpose_conv<<<dim3(2048 / 64, 2048 / 64), 256, 0, stream>>>(W_o, WoT, 2048, 2048);
  rope_table<<<dim3(512), 256, 0, stream>>>(ct, st);

  gemm_bt<0><<<dim3(512 / 128, BS_ / 128), 256, 0, stream>>>(xb, WdkvT, b_dkv, kvb, BS_, 512, 2048);
  gemm_bt<0><<<dim3(1536 / 128, BS_ / 128), 256, 0, stream>>>(xb, WdqT, b_dq, q1b, BS_, 1536, 2048);
  // xb dead from here on
  gemm_bt<0><<<dim3(2048 / 128, BS_ / 128), 256, 0, stream>>>(kvb, WukT, b_uk, kb, BS_, 2048, 512);
  gemm_bt<0><<<dim3(2048 / 128, BS_ / 128), 256, 0, stream>>>(kvb, WuvT, b_uv, vb, BS_, 2048, 512);
  gemm_bt<0><<<dim3(2048 / 128, BS_ / 128), 256, 0, stream>>>(q1b, WuqT, b_uq, qb, BS_, 2048, 1536);

  rope_apply<<<dim3(BS_ * 1024 / 256), 256, 0, stream>>>((u32*)qb, ct, st);
  rope_apply<<<dim3(BS_ * 1024 / 256), 256, 0, stream>>>((u32*)kb, ct, st);
  vtrans<<<dim3(S_ / 64, 32), 256, 0, stream>>>(vb, VT);

  attn_kernel<<<dim3(512), 256, 0, stream>>>(qb, kb, VT, aob);

  gemm_bt<1><<<dim3(2048 / 128, BS_ / 128), 256, 0, stream>>>(aob, WoT, b_o, out, BS_, 2048, 2048);
}

// Round 7
// 316.976 us; speedup vs baseline: 1.3405x; 1.1152x over previous
//
#include <hip/hip_runtime.h>
#include <stdint.h>

typedef unsigned short u16;
typedef uint32_t u32;
typedef __attribute__((ext_vector_type(8))) short short8;
typedef __attribute__((ext_vector_type(4))) float f32x4;
typedef __attribute__((ext_vector_type(4))) u32 u32x4;
typedef __attribute__((ext_vector_type(2))) u32 u32x2;
typedef __attribute__((ext_vector_type(4))) unsigned short u16x4;

#define BS_ 4096   // B*S rows
#define S_ 2048
#define HID_ 2048
#define KVB 64

__device__ __forceinline__ float bf2f(u16 u) { union { u32 i; float f; } v; v.i = ((u32)u) << 16; return v.f; }
__device__ __forceinline__ u16 f2bf(float f) {
  union { float f; u32 i; } v; v.f = f;
  u32 r = v.i + 0x7fffu + ((v.i >> 16) & 1u);
  return (u16)(r >> 16);
}

__device__ __forceinline__ void gload16(const void* gsrc, void* ldst) {
  __builtin_amdgcn_global_load_lds(
      (const __attribute__((address_space(1))) void*)gsrc,
      (__attribute__((address_space(3))) void*)ldst, 16, 0, 0);
}

// ---------------- elementwise convert fp32 -> bf16 ----------------
__global__ __launch_bounds__(256) void conv_f2b(const float* __restrict__ in, u16* __restrict__ out, int n4) {
  int i = blockIdx.x * 256 + threadIdx.x;
  if (i < n4) {
    float4 v = ((const float4*)in)[i];
    u16x4 o;
    o.x = f2bf(v.x); o.y = f2bf(v.y); o.z = f2bf(v.z); o.w = f2bf(v.w);
    ((u16x4*)out)[i] = o;
  }
}

// ---------------- transpose + convert: W[K][N] fp32 -> WT[N][K] bf16 ----------------
__global__ __launch_bounds__(256) void transpose_conv(const float* __restrict__ W, u16* __restrict__ WT,
                                                      int K, int N) {
  __shared__ float tile[64][65];
  const int t = threadIdx.x;
  const int kb = blockIdx.y * 64, nb = blockIdx.x * 64;
#pragma unroll
  for (int c = 0; c < 4; ++c) {
    int idx = c * 256 + t;
    int row = idx >> 4;
    int col4 = (idx & 15) * 4;
    float4 v = *(const float4*)&W[(size_t)(kb + row) * N + nb + col4];
    tile[row][col4 + 0] = v.x; tile[row][col4 + 1] = v.y;
    tile[row][col4 + 2] = v.z; tile[row][col4 + 3] = v.w;
  }
  __syncthreads();
#pragma unroll
  for (int c = 0; c < 4; ++c) {
    int idx = c * 256 + t;
    int n = idx >> 4;
    int k4 = (idx & 15) * 4;
    u16x4 o;
    o.x = f2bf(tile[k4 + 0][n]); o.y = f2bf(tile[k4 + 1][n]);
    o.z = f2bf(tile[k4 + 2][n]); o.w = f2bf(tile[k4 + 3][n]);
    *(u16x4*)&WT[(size_t)(nb + n) * K + kb + k4] = o;
  }
}

// ---------------- bias concat: bc1 = {b_dkv|b_dq} (2048), bc2 = {b_uk|b_uv} (4096) ----------------
__global__ __launch_bounds__(256) void concat_bias(const float* __restrict__ b_dkv, const float* __restrict__ b_dq,
                                                   const float* __restrict__ b_uk, const float* __restrict__ b_uv,
                                                   float* __restrict__ bc1, float* __restrict__ bc2) {
  int i = blockIdx.x * 256 + threadIdx.x;   // 0..6143
  if (i < 512) bc1[i] = b_dkv[i];
  else if (i < 2048) bc1[i] = b_dq[i - 512];
  else if (i < 4096) bc2[i - 2048] = b_uk[i - 2048];
  else if (i < 6144) bc2[i - 2048] = b_uv[i - 4096];
}

// ---------------- V transpose: kvbuf[b][s][2048 + h*128 + d] -> VT[(b*16+h)][d][s] ----------------
__global__ __launch_bounds__(256) void vtrans(const u16* __restrict__ KVin, u16* __restrict__ VT) {
  __shared__ u16 tile[64][136];
  const int t = threadIdx.x;
  const int st0 = blockIdx.x * 64;
  const int bh = blockIdx.y;
  const int bb = bh >> 4, h = bh & 15;
  const u16* src = KVin + (size_t)bb * S_ * 4096 + 2048 + (size_t)h * 128;
  u16* dst = VT + (size_t)bh * 128 * S_;
#pragma unroll
  for (int c = 0; c < 4; ++c) {
    int idx = c * 256 + t;
    int s = idx >> 4, ch = idx & 15;
    short8 v = *(const short8*)&src[(size_t)(st0 + s) * 4096 + ch * 8];
    *(short8*)&tile[s][ch * 8] = v;
  }
  __syncthreads();
#pragma unroll
  for (int c = 0; c < 4; ++c) {
    int idx = c * 256 + t;
    int d = idx >> 3, ch = idx & 7;
    short8 o;
#pragma unroll
    for (int j = 0; j < 8; ++j) o[j] = tile[ch * 8 + j][d];
    *(short8*)&dst[(size_t)d * S_ + st0 + ch * 8] = o;
  }
}

// ---------------- RoPE table ----------------
__global__ __launch_bounds__(256) void rope_table(float* __restrict__ ct, float* __restrict__ st) {
  int idx = blockIdx.x * 256 + threadIdx.x;
  int pos = idx >> 6, i = idx & 63;
  float inv = powf(10000.f, -(float)i / 64.f);
  float a = (float)pos * inv;
  ct[idx] = cosf(a);
  st[idx] = sinf(a);
}

// ---------------- RoPE apply: stride-aware (pairs per row), first 1024 pairs of each row ----------------
__global__ __launch_bounds__(256) void rope_apply(u32* __restrict__ buf, const float* __restrict__ ct,
                                                  const float* __restrict__ st, int row_stride_pairs) {
  int idx = blockIdx.x * 256 + threadIdx.x;   // 4096*1024
  int row = idx >> 10, cp = idx & 1023;
  int s = row & 2047;
  int i = cp & 63;
  size_t a = (size_t)row * row_stride_pairs + cp;
  u32 v = buf[a];
  float x1 = bf2f((u16)(v & 0xffff)), x2 = bf2f((u16)(v >> 16));
  float c = ct[s * 64 + i], sn = st[s * 64 + i];
  float o1 = x1 * c - x2 * sn;
  float o2 = x1 * sn + x2 * c;
  buf[a] = (u32)f2bf(o1) | ((u32)f2bf(o2) << 16);
}

// ---------------- GEMM v2: swapped-operand epilogue, lda param, XCD swizzle ----------------
// C[M][N] = A[M rows, lda stride][0..K) * BT[N][K]^T + bias
template <int OUTF32>
__global__ __launch_bounds__(256) void gemm_bt(const u16* __restrict__ A, int lda,
                                               const u16* __restrict__ BT,
                                               const float* __restrict__ bias, void* __restrict__ Cout,
                                               int M, int N, int K) {
  __shared__ u16 As[128 * 64];
  __shared__ u16 Bs[128 * 64];
  const int t = threadIdx.x;
  const int lane = t & 63, wave = t >> 6;
  const int wm = wave >> 1, wn = wave & 1;
  const int gx = gridDim.x;
  const int nwg = gx * gridDim.y;
  const int flat = blockIdx.y * gx + blockIdx.x;
  const int swz = (flat & 7) * (nwg >> 3) + (flat >> 3);
  const int tn = swz % gx, tm = swz / gx;
  const int r16 = lane & 15, q4 = lane >> 4;

  f32x4 acc[4][4];
#pragma unroll
  for (int m = 0; m < 4; ++m)
#pragma unroll
    for (int n = 0; n < 4; ++n) acc[m][n] = (f32x4){0.f, 0.f, 0.f, 0.f};

  for (int kt = 0; kt < K; kt += 64) {
#pragma unroll
    for (int c = 0; c < 4; ++c) {
      int idx = c * 256 + t;
      int row = idx >> 3, ch = idx & 7;
      gload16(&A[(size_t)(tm * 128 + row) * lda + kt + ch * 8], (char*)As + idx * 16);
      gload16(&BT[(size_t)(tn * 128 + row) * K + kt + ch * 8], (char*)Bs + idx * 16);
    }
    __syncthreads();
#pragma unroll
    for (int kk = 0; kk < 64; kk += 32) {
      short8 af[4], bfv[4];
#pragma unroll
      for (int m = 0; m < 4; ++m)
        af[m] = *(const short8*)&As[(wm * 64 + m * 16 + r16) * 64 + kk + q4 * 8];
#pragma unroll
      for (int n = 0; n < 4; ++n)
        bfv[n] = *(const short8*)&Bs[(wn * 64 + n * 16 + r16) * 64 + kk + q4 * 8];
      __builtin_amdgcn_s_setprio(1);
      // swapped operands: D col (lane&15) = M-row, D row (q4*4+j) = N-col
#pragma unroll
      for (int m = 0; m < 4; ++m)
#pragma unroll
        for (int n = 0; n < 4; ++n)
          acc[m][n] = __builtin_amdgcn_mfma_f32_16x16x32_bf16(bfv[n], af[m], acc[m][n], 0, 0, 0);
      __builtin_amdgcn_s_setprio(0);
    }
    __syncthreads();
  }
  // epilogue: per (m,n) one contiguous 4-wide store per lane
#pragma unroll
  for (int n = 0; n < 4; ++n) {
    int gc0 = tn * 128 + wn * 64 + n * 16 + q4 * 4;
    float4 bv4 = *(const float4*)&bias[gc0];
#pragma unroll
    for (int m = 0; m < 4; ++m) {
      int grow = tm * 128 + wm * 64 + m * 16 + r16;
      if (OUTF32) {
        float4 o;
        o.x = acc[m][n][0] + bv4.x; o.y = acc[m][n][1] + bv4.y;
        o.z = acc[m][n][2] + bv4.z; o.w = acc[m][n][3] + bv4.w;
        *(float4*)&((float*)Cout)[(size_t)grow * N + gc0] = o;
      } else {
        u16x4 o;
        o.x = f2bf(acc[m][n][0] + bv4.x); o.y = f2bf(acc[m][n][1] + bv4.y);
        o.z = f2bf(acc[m][n][2] + bv4.z); o.w = f2bf(acc[m][n][3] + bv4.w);
        *(u16x4*)&((u16*)Cout)[(size_t)grow * N + gc0] = o;
      }
    }
  }
}

// ---------------- causal flash attention v6 (unchanged except K row-stride param) ----------------
__global__ __launch_bounds__(256, 2) void attn_kernel(const u16* __restrict__ Q, const u16* __restrict__ K,
                                                      int kld, const u16* __restrict__ VT,
                                                      u16* __restrict__ O) {
  __shared__ u16 Kl[2][KVB * 128];
  __shared__ u16 Vl[2][128 * KVB];
  __shared__ u16 Pl[4][16 * 64];
  const int t = threadIdx.x;
  const int lane = t & 63, w = t >> 6;
  const int r16 = lane & 15, q4 = lane >> 4;
  const int b = blockIdx.x;
  const int xcd = b & 7, u = b >> 3;
  const int p = u & 15, g4 = u >> 4;
  const int bh = g4 * 8 + xcd;
  const int bb = bh >> 4, h = bh & 15;
  const u16* Qb = Q + (size_t)bb * S_ * HID_ + (size_t)h * 128;
  const u16* Kb = K + (size_t)bb * S_ * kld + (size_t)h * 128;
  const u16* VTb = VT + (size_t)bh * 128 * S_;
  u16* Ob = O + (size_t)bb * S_ * HID_ + (size_t)h * 128;

  auto stage = [&](int buf, int kvbase) {
#pragma unroll
    for (int c = 0; c < 4; ++c) {
      int s = c * 256 + t;
      int row = s >> 4;
      int chs = (s & 15) ^ (row & 7);
      gload16(&Kb[(size_t)(kvbase + row) * kld + chs * 8], (char*)Kl[buf] + s * 16);
    }
#pragma unroll
    for (int c = 0; c < 4; ++c) {
      int s = c * 256 + t;
      int row = s >> 3;
      int chs = (s & 7) ^ (row & 7);
      gload16(&VTb[(size_t)row * S_ + kvbase + chs * 8], (char*)Vl[buf] + s * 16);
    }
  };

  u16* Pw = &Pl[w][0];
  const float SCALE = 0.08838834764831845f;

#pragma unroll
  for (int seg = 0; seg < 2; ++seg) {
    const int qt = seg ? (31 - p) : p;
    const int nt = qt + 1;
    const int qrow0 = qt * 64 + w * 16;
    const int q = qrow0 + r16;

    short8 qf[4];
#pragma unroll
    for (int dk = 0; dk < 4; ++dk)
      qf[dk] = *(const short8*)&Qb[(size_t)q * HID_ + dk * 32 + q4 * 8];

    f32x4 ao[8];
#pragma unroll
    for (int dn = 0; dn < 8; ++dn) ao[dn] = (f32x4){0.f, 0.f, 0.f, 0.f};
    float mr = -1e30f, lr = 0.f;

    stage(0, 0);
    __syncthreads();

    for (int ti = 0; ti < nt; ++ti) {
      const int buf = ti & 1;
      const int kv0 = ti * KVB;
      if (ti + 1 < nt) stage(buf ^ 1, kv0 + KVB);

      f32x4 sc[4];
#pragma unroll
      for (int n = 0; n < 4; ++n) sc[n] = (f32x4){0.f, 0.f, 0.f, 0.f};
#pragma unroll
      for (int dk = 0; dk < 4; ++dk) {
        short8 kf[4];
#pragma unroll
        for (int n = 0; n < 4; ++n) {
          int kr = n * 16 + r16;
          int ba = (kr * 256 + dk * 64 + q4 * 16) ^ ((kr & 7) << 4);
          kf[n] = *(const short8*)((const char*)Kl[buf] + ba);
        }
        __builtin_amdgcn_s_setprio(1);
#pragma unroll
        for (int n = 0; n < 4; ++n)
          sc[n] = __builtin_amdgcn_mfma_f32_16x16x32_bf16(kf[n], qf[dk], sc[n], 0, 0, 0);
        __builtin_amdgcn_s_setprio(0);
      }
      const bool nm = (kv0 + 63 > qrow0);
#pragma unroll
      for (int n = 0; n < 4; ++n)
#pragma unroll
        for (int j = 0; j < 4; ++j) {
          float sv = sc[n][j] * SCALE;
          if (nm) {
            int kv = kv0 + n * 16 + q4 * 4 + j;
            if (kv > q) sv = -1e30f;
          }
          sc[n][j] = sv;
        }
      float tm = sc[0][0];
#pragma unroll
      for (int n = 0; n < 4; ++n)
#pragma unroll
        for (int j = 0; j < 4; ++j) tm = fmaxf(tm, sc[n][j]);
      tm = fmaxf(tm, __shfl_xor(tm, 16));
      tm = fmaxf(tm, __shfl_xor(tm, 32));
      if (!__all(tm - mr <= 8.0f)) {
        float mnew = fmaxf(mr, tm);
        float fsc = __expf(mr - mnew);
        lr *= fsc; mr = mnew;
#pragma unroll
        for (int dn = 0; dn < 8; ++dn) ao[dn] *= fsc;
      }
      float ps = 0.f;
#pragma unroll
      for (int n = 0; n < 4; ++n)
#pragma unroll
        for (int j = 0; j < 4; ++j) {
          float pv = __expf(sc[n][j] - mr);
          sc[n][j] = pv;
          ps += pv;
        }
      ps += __shfl_xor(ps, 16);
      ps += __shfl_xor(ps, 32);
      lr += ps;
#pragma unroll
      for (int n = 0; n < 4; ++n) {
        u32 lo, hi;
        asm("v_cvt_pk_bf16_f32 %0, %1, %2" : "=v"(lo) : "v"(sc[n][0]), "v"(sc[n][1]));
        asm("v_cvt_pk_bf16_f32 %0, %1, %2" : "=v"(hi) : "v"(sc[n][2]), "v"(sc[n][3]));
        u32x2 pr; pr.x = lo; pr.y = hi;
        int ba = (r16 * 128 + n * 32 + q4 * 8) ^ ((r16 & 7) << 4);
        *(u32x2*)((char*)Pw + ba) = pr;
      }
#pragma unroll
      for (int s = 0; s < 2; ++s) {
        int bp = (r16 * 128 + s * 64 + q4 * 16) ^ ((r16 & 7) << 4);
        short8 pb = *(const short8*)((const char*)Pw + bp);
        __builtin_amdgcn_s_setprio(1);
#pragma unroll
        for (int dn = 0; dn < 8; ++dn) {
          int dr = dn * 16 + r16;
          int bv = (dr * 128 + s * 64 + q4 * 16) ^ ((dr & 7) << 4);
          short8 vf = *(const short8*)((const char*)Vl[buf] + bv);
          ao[dn] = __builtin_amdgcn_mfma_f32_16x16x32_bf16(vf, pb, ao[dn], 0, 0, 0);
        }
        __builtin_amdgcn_s_setprio(0);
      }
      __syncthreads();
    }

    float inv = 1.f / lr;
#pragma unroll
    for (int dn = 0; dn < 8; ++dn) {
      u16x4 o;
#pragma unroll
      for (int j = 0; j < 4; ++j) o[j] = f2bf(ao[dn][j] * inv);
      *(u16x4*)&Ob[(size_t)q * HID_ + dn * 16 + q4 * 4] = o;
    }
    __syncthreads();
  }
}

// ---------------- host launch ----------------
extern "C" void kernel_launch(void* const* d_in, const int* in_sizes, int n_in,
                              void* d_out, int out_size, void* d_ws, size_t ws_size,
                              hipStream_t stream) {
  (void)in_sizes; (void)n_in; (void)out_size; (void)ws_size;
  const float* x     = (const float*)d_in[0];
  const float* W_dkv = (const float*)d_in[2];
  const float* b_dkv = (const float*)d_in[3];
  const float* W_uk  = (const float*)d_in[4];
  const float* b_uk  = (const float*)d_in[5];
  const float* W_uv  = (const float*)d_in[6];
  const float* b_uv  = (const float*)d_in[7];
  const float* W_dq  = (const float*)d_in[8];
  const float* b_dq  = (const float*)d_in[9];
  const float* W_uq  = (const float*)d_in[10];
  const float* b_uq  = (const float*)d_in[11];
  const float* W_o   = (const float*)d_in[12];
  const float* b_o   = (const float*)d_in[13];
  float* out = (float*)d_out;

  char* ws = (char*)d_ws;
  size_t off = 0;
  auto carve = [&](size_t bytes) { void* p = ws + off; off += (bytes + 255) & ~(size_t)255; return p; };
  u16* xb     = (u16*)carve((size_t)BS_ * 2048 * 2);      // reused as VT after GEMM1
  u16* WdkvqT = (u16*)carve((size_t)2048 * 2048 * 2);     // rows 0-511 dkv, 512-2047 dq
  u16* WukvT  = (u16*)carve((size_t)4096 * 512 * 2);      // rows 0-2047 uk, 2048-4095 uv
  u16* WuqT   = (u16*)carve((size_t)2048 * 1536 * 2);
  u16* WoT    = (u16*)carve((size_t)2048 * 2048 * 2);
  u16* kvq1   = (u16*)carve((size_t)BS_ * 2048 * 2);      // cols 0-511 kv, 512-2047 q1
  u16* kvbuf  = (u16*)carve((size_t)BS_ * 4096 * 2);      // cols 0-2047 k, 2048-4095 v
  u16* qb     = (u16*)carve((size_t)BS_ * 2048 * 2);
  u16* aob    = (u16*)carve((size_t)BS_ * 2048 * 2);
  float* ct   = (float*)carve((size_t)2048 * 64 * 4);
  float* st   = (float*)carve((size_t)2048 * 64 * 4);
  float* bc1  = (float*)carve((size_t)2048 * 4);
  float* bc2  = (float*)carve((size_t)4096 * 4);
  u16* VT     = xb;   // xb dead after GEMM1

  conv_f2b<<<dim3(BS_ * 2048 / 4 / 256), 256, 0, stream>>>(x, xb, BS_ * 2048 / 4);
  transpose_conv<<<dim3(512 / 64, 2048 / 64), 256, 0, stream>>>(W_dkv, WdkvqT, 2048, 512);
  transpose_conv<<<dim3(1536 / 64, 2048 / 64), 256, 0, stream>>>(W_dq, WdkvqT + (size_t)512 * 2048, 2048, 1536);
  transpose_conv<<<dim3(2048 / 64, 512 / 64), 256, 0, stream>>>(W_uk, WukvT, 512, 2048);
  transpose_conv<<<dim3(2048 / 64, 512 / 64), 256, 0, stream>>>(W_uv, WukvT + (size_t)2048 * 512, 512, 2048);
  transpose_conv<<<dim3(2048 / 64, 1536 / 64), 256, 0, stream>>>(W_uq, WuqT, 1536, 2048);
  transpose_conv<<<dim3(2048 / 64, 2048 / 64), 256, 0, stream>>>(W_o, WoT, 2048, 2048);
  rope_table<<<dim3(512), 256, 0, stream>>>(ct, st);
  concat_bias<<<dim3(24), 256, 0, stream>>>(b_dkv, b_dq, b_uk, b_uv, bc1, bc2);

  // GEMM1: x @ {W_dkv|W_dq} -> kvq1 [4096][2048]
  gemm_bt<0><<<dim3(2048 / 128, BS_ / 128), 256, 0, stream>>>(xb, 2048, WdkvqT, bc1, kvq1, BS_, 2048, 2048);
  // GEMM2: kv @ {W_uk|W_uv} -> kvbuf [4096][4096]  (A = first 512 cols of kvq1)
  gemm_bt<0><<<dim3(4096 / 128, BS_ / 128), 256, 0, stream>>>(kvq1, 2048, WukvT, bc2, kvbuf, BS_, 4096, 512);
  // GEMM3: q1 @ W_uq -> qb [4096][2048]  (A = cols 512.. of kvq1)
  gemm_bt<0><<<dim3(2048 / 128, BS_ / 128), 256, 0, stream>>>(kvq1 + 512, 2048, WuqT, b_uq, qb, BS_, 2048, 1536);

  rope_apply<<<dim3(BS_ * 1024 / 256), 256, 0, stream>>>((u32*)qb, ct, st, 1024);
  rope_apply<<<dim3(BS_ * 1024 / 256), 256, 0, stream>>>((u32*)kvbuf, ct, st, 2048);
  vtrans<<<dim3(S_ / 64, 32), 256, 0, stream>>>(kvbuf, VT);

  attn_kernel<<<dim3(512), 256, 0, stream>>>(qb, kvbuf, 4096, VT, aob);

  // GEMM4: attn_out @ W_o -> out (fp32)
  gemm_bt<1><<<dim3(2048 / 128, BS_ / 128), 256, 0, stream>>>(aob, 2048, WoT, b_o, out, BS_, 2048, 2048);
}